// Round 3
// baseline (301.345 us; speedup 1.0000x reference)
//
#include <hip/hip_runtime.h>

#define NV_N 32
#define NV_C 128
#define NV_K 64
#define NV_S 12544
#define ST 64          // s-columns per tile
#define TILES 14       // tiles per block
#define SCHUNK 14      // blocks per image
#define XS 72          // x_lds row stride (bf16 elems), 144 B: 16B-aligned rows
#define AS 72          // a_lds row stride

typedef short short8 __attribute__((ext_vector_type(8)));
typedef float floatx4 __attribute__((ext_vector_type(4)));

static __device__ __forceinline__ unsigned short f2bf(float f) {
  union { float f; unsigned u; } v; v.f = f;
  unsigned r = v.u + 0x7FFFu + ((v.u >> 16) & 1u);  // RNE
  return (unsigned short)(r >> 16);
}

static __device__ __forceinline__ short8 pack8(float4 a, float4 b) {
  union { unsigned short us[8]; short8 s; } u;
  u.us[0] = f2bf(a.x); u.us[1] = f2bf(a.y); u.us[2] = f2bf(a.z); u.us[3] = f2bf(a.w);
  u.us[4] = f2bf(b.x); u.us[5] = f2bf(b.y); u.us[6] = f2bf(b.z); u.us[7] = f2bf(b.w);
  return u.s;
}

// x_lds layout: row-major [c][XS] with the 8 in-row 8-elem granules rotated by
// (c>>3)&7:  elemoff(c,s) = c*XS + (((s>>3) + (c>>3)) & 7)*8 + (s&7)
// All accesses (stage write: 8 consecutive s, granule-aligned; GEMM1: single
// elem; GEMM2: 8 consecutive s, granule-aligned) respect granule boundaries,
// so this is a pure permutation. It makes GEMM1's column-gather bank index
// depend on q (via the c>>3 rotation), breaking the 8-way conflict that a
// plain stride-72 row-major layout has (q*8 rows * 36 dwords ≡ 0 mod 32).

__global__ __launch_bounds__(256, 2) void netvlad_main(
    const float* __restrict__ x, const float* __restrict__ conv_w,
    float* __restrict__ vlad_part, float* __restrict__ asum_part) {
  __shared__ __attribute__((aligned(16))) unsigned short x_lds[2][NV_C * XS]; // 36864 B
  __shared__ __attribute__((aligned(16))) unsigned short a_lds[NV_K * AS];    //  9216 B
  __shared__ float asum_sh[4][NV_K];                                          //  1024 B

  const int t = threadIdx.x;
  const int n = blockIdx.x / SCHUNK;
  const int chunk = blockIdx.x % SCHUNK;
  const int s_base = chunk * (ST * TILES);
  const int w = t >> 6;        // wave 0..3
  const int lane = t & 63;
  const int q = lane >> 4;     // quad 0..3
  const int l = lane & 15;

  const float* __restrict__ xn = x + (size_t)n * NV_C * NV_S;

  // ---- preload W as A-operand fragments: lane holds W[mt*16+l][kc*32+q*8+j] ----
  short8 wfrag[4][4];
#pragma unroll
  for (int mt = 0; mt < 4; ++mt)
#pragma unroll
    for (int kc = 0; kc < 4; ++kc) {
      const float* wp = conv_w + (mt * 16 + l) * NV_C + kc * 32 + q * 8;
      float4 wa = *(const float4*)wp;
      float4 wb = *(const float4*)(wp + 4);
      wfrag[mt][kc] = pack8(wa, wb);
    }

  floatx4 acc2[4][2];   // vlad accumulators: k=mt*16+q*4+r, c=(w*2+nt)*16+l
  float asum_acc[4][4];
#pragma unroll
  for (int mt = 0; mt < 4; ++mt) {
#pragma unroll
    for (int nt = 0; nt < 2; ++nt) acc2[mt][nt] = (floatx4){0.f, 0.f, 0.f, 0.f};
#pragma unroll
    for (int r = 0; r < 4; ++r) asum_acc[mt][r] = 0.f;
  }

  // ---- staging slots (tile-invariant) ----
  int wroff[4]; const float* gp[4];
#pragma unroll
  for (int g = 0; g < 4; ++g) {
    int vec2 = t + g * 256; int c = vec2 >> 3; int sv8 = vec2 & 7;
    wroff[g] = c * XS + (((sv8 + (c >> 3)) & 7) << 3);
    gp[g] = xn + (size_t)c * NV_S + s_base + sv8 * 8;
  }

  float4 pf[8];
#pragma unroll
  for (int g = 0; g < 4; ++g) {
    pf[2 * g] = *(const float4*)gp[g];
    pf[2 * g + 1] = *(const float4*)(gp[g] + 4);
  }

  for (int tt = 0; tt < TILES; ++tt) {
    const int buf = tt & 1;
    // ---- convert + write staged tile to LDS (bf16, granule-rotated) ----
#pragma unroll
    for (int g = 0; g < 4; ++g)
      *(short8*)&x_lds[buf][wroff[g]] = pack8(pf[2 * g], pf[2 * g + 1]);
    __syncthreads();

    // ---- issue prefetch for tile tt+1 (consumed next iteration) ----
    if (tt + 1 < TILES) {
      const int soff = (tt + 1) * ST;
#pragma unroll
      for (int g = 0; g < 4; ++g) {
        pf[2 * g] = *(const float4*)(gp[g] + soff);
        pf[2 * g + 1] = *(const float4*)(gp[g] + soff + 4);
      }
    }

    // ---- GEMM1: logits[64 k][16 s(wave)] = W(64x128) * x(128x64-tile) ----
    floatx4 acc1[4];
#pragma unroll
    for (int mt = 0; mt < 4; ++mt) acc1[mt] = (floatx4){0.f, 0.f, 0.f, 0.f};
#pragma unroll
    for (int kc = 0; kc < 4; ++kc) {
      // B-frag: lane needs x[c = kc*32+q*8+j][s = w*16+l], j=0..7
      // granule = (w*2 + (l>>3) + kc*4 + q) & 7  (since (kc*32+q*8+j)>>3 == kc*4+q)
      const int gsel = (w * 2 + (l >> 3) + kc * 4 + q) & 7;
      short8 bfr;
#pragma unroll
      for (int j = 0; j < 8; ++j)
        bfr[j] = (short)x_lds[buf][(kc * 32 + q * 8 + j) * XS + (gsel << 3) + (l & 7)];
#pragma unroll
      for (int mt = 0; mt < 4; ++mt)
        acc1[mt] = __builtin_amdgcn_mfma_f32_16x16x32_bf16(wfrag[mt][kc], bfr, acc1[mt], 0, 0, 0);
    }

    // ---- softmax over k (64) per column s; all in registers ----
    {
      float m = -1e30f;
#pragma unroll
      for (int mt = 0; mt < 4; ++mt)
#pragma unroll
        for (int r = 0; r < 4; ++r) m = fmaxf(m, acc1[mt][r]);
      m = fmaxf(m, __shfl_xor(m, 16));
      m = fmaxf(m, __shfl_xor(m, 32));
      float sum = 0.f;
#pragma unroll
      for (int mt = 0; mt < 4; ++mt)
#pragma unroll
        for (int r = 0; r < 4; ++r) {
          float e = __expf(acc1[mt][r] - m);
          acc1[mt][r] = e; sum += e;
        }
      sum += __shfl_xor(sum, 16);
      sum += __shfl_xor(sum, 32);
      const float inv = 1.0f / sum;
#pragma unroll
      for (int mt = 0; mt < 4; ++mt)
#pragma unroll
        for (int r = 0; r < 4; ++r) {
          float a = acc1[mt][r] * inv;
          asum_acc[mt][r] += a;
          a_lds[(mt * 16 + q * 4 + r) * AS + w * 16 + l] = f2bf(a);
        }
    }
    __syncthreads();

    // ---- GEMM2: vlad[64 k][128 c] += a(64 x 64s) * x^T(64s x 128c) ----
#pragma unroll
    for (int sk = 0; sk < 2; ++sk) {
      short8 afr[4];
#pragma unroll
      for (int mt = 0; mt < 4; ++mt)
        afr[mt] = *(const short8*)&a_lds[(mt * 16 + l) * AS + sk * 32 + q * 8];
#pragma unroll
      for (int nt = 0; nt < 2; ++nt) {
        const int c2 = (w * 2 + nt) * 16 + l;
        const int gsel2 = (sk * 4 + q + (c2 >> 3)) & 7;   // stored granule of s0=sk*32+q*8
        const short8 bfr = *(const short8*)&x_lds[buf][c2 * XS + (gsel2 << 3)];
#pragma unroll
        for (int mt = 0; mt < 4; ++mt)
          acc2[mt][nt] = __builtin_amdgcn_mfma_f32_16x16x32_bf16(afr[mt], bfr, acc2[mt][nt], 0, 0, 0);
      }
    }
  }

  // ---- epilogue: per-block partial slices, no atomics ----
#pragma unroll
  for (int mt = 0; mt < 4; ++mt)
#pragma unroll
    for (int r = 0; r < 4; ++r) {
      float v = asum_acc[mt][r];
      v += __shfl_xor(v, 1); v += __shfl_xor(v, 2);
      v += __shfl_xor(v, 4); v += __shfl_xor(v, 8);
      if (l == 0) asum_sh[w][mt * 16 + q * 4 + r] = v;
    }
  __syncthreads();
  if (t < NV_K)
    asum_part[(size_t)blockIdx.x * NV_K + t] =
        asum_sh[0][t] + asum_sh[1][t] + asum_sh[2][t] + asum_sh[3][t];

  float* vp = vlad_part + (size_t)blockIdx.x * (NV_K * NV_C);
#pragma unroll
  for (int mt = 0; mt < 4; ++mt)
#pragma unroll
    for (int nt = 0; nt < 2; ++nt)
#pragma unroll
      for (int r = 0; r < 4; ++r)
        vp[(mt * 16 + q * 4 + r) * NV_C + (w * 2 + nt) * 16 + l] = acc2[mt][nt][r];
}

__global__ __launch_bounds__(256) void netvlad_finalize(
    const float* __restrict__ vlad_part, const float* __restrict__ asum_part,
    const float* __restrict__ cent, float* __restrict__ out) {
  __shared__ float v_lds[NV_K * NV_C];  // 32 KB
  __shared__ float red4[256];
  __shared__ float rscale[NV_K];
  __shared__ float asum_tot[NV_K];
  __shared__ float gscale_sh;

  const int t = threadIdx.x; const int n = blockIdx.x;
  const float* vp = vlad_part + (size_t)n * SCHUNK * (NV_K * NV_C);

  if (t < NV_K) {
    float s = 0.f;
#pragma unroll
    for (int ch = 0; ch < SCHUNK; ++ch)
      s += asum_part[((size_t)n * SCHUNK + ch) * NV_K + t];
    asum_tot[t] = s;
  }
  __syncthreads();

#pragma unroll
  for (int i = 0; i < 8; ++i) {
    int vec = t + i * 256; int k = vec >> 5; int cq = vec & 31;
    float ax = 0.f, ay = 0.f, az = 0.f, aw = 0.f;
#pragma unroll
    for (int ch = 0; ch < SCHUNK; ++ch) {
      float4 p = *(const float4*)(vp + (size_t)ch * (NV_K * NV_C) + k * NV_C + cq * 4);
      ax += p.x; ay += p.y; az += p.z; aw += p.w;
    }
    float4 ce = *(const float4*)(cent + k * NV_C + cq * 4);
    float as = asum_tot[k];
    float4 v;
    v.x = ax - as * ce.x; v.y = ay - as * ce.y;
    v.z = az - as * ce.z; v.w = aw - as * ce.w;
    *(float4*)&v_lds[k * NV_C + cq * 4] = v;
  }
  __syncthreads();

  {  // per-cluster sumsq
    const int k = t >> 2, part = t & 3;
    const float* row = &v_lds[k * NV_C + part * 32];
    float ss = 0.0f;
#pragma unroll
    for (int c = 0; c < 32; ++c) { float v = row[c]; ss += v * v; }
    red4[t] = ss;
  }
  __syncthreads();
  if (t < NV_K) {
    float ss = red4[t * 4] + red4[t * 4 + 1] + red4[t * 4 + 2] + red4[t * 4 + 3];
    rscale[t] = 1.0f / fmaxf(sqrtf(ss), 1e-12f);
  }
  __syncthreads();

  float gp = 0.0f;
#pragma unroll
  for (int i = 0; i < 8; ++i) {
    int vec = t + i * 256; int k = vec >> 5; int cq = vec & 31;
    float4 v = *(const float4*)&v_lds[k * NV_C + cq * 4];
    float rs = rscale[k];
    gp += (v.x * v.x + v.y * v.y + v.z * v.z + v.w * v.w) * rs * rs;
  }
  red4[t] = gp;
  __syncthreads();
  if (t < 64) {
    float s = red4[t] + red4[t + 64] + red4[t + 128] + red4[t + 192];
#pragma unroll
    for (int o = 32; o > 0; o >>= 1) s += __shfl_down(s, o);
    if (t == 0) gscale_sh = 1.0f / fmaxf(sqrtf(s), 1e-12f);
  }
  __syncthreads();
  const float gs = gscale_sh;

#pragma unroll
  for (int i = 0; i < 8; ++i) {
    int vec = t + i * 256; int k = vec >> 5; int cq = vec & 31;
    float4 v = *(const float4*)&v_lds[k * NV_C + cq * 4];
    const float sc = rscale[k] * gs;
    v.x *= sc; v.y *= sc; v.z *= sc; v.w *= sc;
    *(float4*)(out + (size_t)n * (NV_K * NV_C) + k * NV_C + cq * 4) = v;
  }
}

extern "C" void kernel_launch(void* const* d_in, const int* in_sizes, int n_in,
                              void* d_out, int out_size, void* d_ws, size_t ws_size,
                              hipStream_t stream) {
  (void)in_sizes; (void)n_in; (void)out_size; (void)ws_size;
  const float* x      = (const float*)d_in[0];
  const float* conv_w = (const float*)d_in[1];
  const float* cent   = (const float*)d_in[2];
  float* out = (float*)d_out;

  // ws: [N*SCHUNK][K][C] partial vlads (14.7 MB) + [N*SCHUNK][K] partial asums
  float* vlad_part = (float*)d_ws;
  float* asum_part = vlad_part + (size_t)NV_N * SCHUNK * NV_K * NV_C;

  hipLaunchKernelGGL(netvlad_main, dim3(NV_N * SCHUNK), dim3(256), 0, stream,
                     x, conv_w, vlad_part, asum_part);
  hipLaunchKernelGGL(netvlad_finalize, dim3(NV_N), dim3(256), 0, stream,
                     vlad_part, asum_part, cent, out);
}

// Round 4
// 299.927 us; speedup vs baseline: 1.0047x; 1.0047x over previous
//
#include <hip/hip_runtime.h>

#define NV_N 32
#define NV_C 128
#define NV_K 64
#define NV_S 12544
#define ST 64          // s-columns per tile
#define SCHUNK 8       // blocks per image: 4 chunks of 25 tiles + 4 of 24 (196 total)
#define XS 72          // x_lds row stride (bf16 elems), 144 B: 16B-aligned rows
#define AS 72          // a_lds row stride

typedef short short8 __attribute__((ext_vector_type(8)));
typedef float floatx4 __attribute__((ext_vector_type(4)));

static __device__ __forceinline__ unsigned short f2bf(float f) {
  union { float f; unsigned u; } v; v.f = f;
  unsigned r = v.u + 0x7FFFu + ((v.u >> 16) & 1u);  // RNE
  return (unsigned short)(r >> 16);
}

static __device__ __forceinline__ short8 pack8(float4 a, float4 b) {
  union { unsigned short us[8]; short8 s; } u;
  u.us[0] = f2bf(a.x); u.us[1] = f2bf(a.y); u.us[2] = f2bf(a.z); u.us[3] = f2bf(a.w);
  u.us[4] = f2bf(b.x); u.us[5] = f2bf(b.y); u.us[6] = f2bf(b.z); u.us[7] = f2bf(b.w);
  return u.s;
}

// x_lds layout: row-major [c][XS] with the 8 in-row 8-elem granules rotated by
// (c>>3)&7:  elemoff(c,s) = c*XS + (((s>>3) + (c>>3)) & 7)*8 + (s&7)
// Pure granule permutation (all accesses granule-aligned or single-elem);
// breaks the 8-way bank conflict of the plain stride-72 column gather.

__global__ __launch_bounds__(256, 2) void netvlad_main(
    const float* __restrict__ x, const float* __restrict__ conv_w,
    float* __restrict__ vlad_part, float* __restrict__ asum_part) {
  __shared__ __attribute__((aligned(16))) unsigned short x_lds[2][NV_C * XS]; // 36864 B
  __shared__ __attribute__((aligned(16))) unsigned short a_lds[NV_K * AS];    //  9216 B
  __shared__ float asum_sh[4][NV_K];                                          //  1024 B

  const int t = threadIdx.x;
  const int n = blockIdx.x / SCHUNK;
  const int chunk = blockIdx.x % SCHUNK;
  // chunks 0..3: 25 tiles, chunks 4..7: 24 tiles (4*25 + 4*24 = 196 = NV_S/ST)
  const int tiles = (chunk < 4) ? 25 : 24;
  const int s_base = (chunk < 4) ? chunk * (25 * ST)
                                 : 4 * (25 * ST) + (chunk - 4) * (24 * ST);
  const int w = t >> 6;        // wave 0..3
  const int lane = t & 63;
  const int q = lane >> 4;     // quad 0..3
  const int l = lane & 15;

  const float* __restrict__ xn = x + (size_t)n * NV_C * NV_S;

  // ---- preload W as A-operand fragments: lane holds W[mt*16+l][kc*32+q*8+j] ----
  short8 wfrag[4][4];
#pragma unroll
  for (int mt = 0; mt < 4; ++mt)
#pragma unroll
    for (int kc = 0; kc < 4; ++kc) {
      const float* wp = conv_w + (mt * 16 + l) * NV_C + kc * 32 + q * 8;
      float4 wa = *(const float4*)wp;
      float4 wb = *(const float4*)(wp + 4);
      wfrag[mt][kc] = pack8(wa, wb);
    }

  floatx4 acc2[4][2];   // vlad accumulators: k=mt*16+q*4+r, c=(w*2+nt)*16+l
  float asum_acc[4][4];
#pragma unroll
  for (int mt = 0; mt < 4; ++mt) {
#pragma unroll
    for (int nt = 0; nt < 2; ++nt) acc2[mt][nt] = (floatx4){0.f, 0.f, 0.f, 0.f};
#pragma unroll
    for (int r = 0; r < 4; ++r) asum_acc[mt][r] = 0.f;
  }

  // ---- staging slots (tile-invariant) ----
  int wroff[4]; const float* gp[4];
#pragma unroll
  for (int g = 0; g < 4; ++g) {
    int vec2 = t + g * 256; int c = vec2 >> 3; int sv8 = vec2 & 7;
    wroff[g] = c * XS + (((sv8 + (c >> 3)) & 7) << 3);
    gp[g] = xn + (size_t)c * NV_S + s_base + sv8 * 8;
  }

  float4 pf[8];
#pragma unroll
  for (int g = 0; g < 4; ++g) {
    pf[2 * g] = *(const float4*)gp[g];
    pf[2 * g + 1] = *(const float4*)(gp[g] + 4);
  }

  for (int tt = 0; tt < tiles; ++tt) {
    const int buf = tt & 1;
    // ---- convert + write staged tile to LDS (bf16, granule-rotated) ----
#pragma unroll
    for (int g = 0; g < 4; ++g)
      *(short8*)&x_lds[buf][wroff[g]] = pack8(pf[2 * g], pf[2 * g + 1]);
    __syncthreads();

    // ---- issue prefetch for tile tt+1 (consumed next iteration) ----
    if (tt + 1 < tiles) {
      const int soff = (tt + 1) * ST;
#pragma unroll
      for (int g = 0; g < 4; ++g) {
        pf[2 * g] = *(const float4*)(gp[g] + soff);
        pf[2 * g + 1] = *(const float4*)(gp[g] + soff + 4);
      }
    }

    // ---- GEMM1: logits[64 k][16 s(wave)] = W(64x128) * x(128x64-tile) ----
    floatx4 acc1[4];
#pragma unroll
    for (int mt = 0; mt < 4; ++mt) acc1[mt] = (floatx4){0.f, 0.f, 0.f, 0.f};
#pragma unroll
    for (int kc = 0; kc < 4; ++kc) {
      // B-frag: lane needs x[c = kc*32+q*8+j][s = w*16+l], j=0..7
      const int gsel = (w * 2 + (l >> 3) + kc * 4 + q) & 7;
      short8 bfr;
#pragma unroll
      for (int j = 0; j < 8; ++j)
        bfr[j] = (short)x_lds[buf][(kc * 32 + q * 8 + j) * XS + (gsel << 3) + (l & 7)];
#pragma unroll
      for (int mt = 0; mt < 4; ++mt)
        acc1[mt] = __builtin_amdgcn_mfma_f32_16x16x32_bf16(wfrag[mt][kc], bfr, acc1[mt], 0, 0, 0);
    }

    // ---- softmax over k (64) per column s; all in registers ----
    {
      float m = -1e30f;
#pragma unroll
      for (int mt = 0; mt < 4; ++mt)
#pragma unroll
        for (int r = 0; r < 4; ++r) m = fmaxf(m, acc1[mt][r]);
      m = fmaxf(m, __shfl_xor(m, 16));
      m = fmaxf(m, __shfl_xor(m, 32));
      float sum = 0.f;
#pragma unroll
      for (int mt = 0; mt < 4; ++mt)
#pragma unroll
        for (int r = 0; r < 4; ++r) {
          float e = __expf(acc1[mt][r] - m);
          acc1[mt][r] = e; sum += e;
        }
      sum += __shfl_xor(sum, 16);
      sum += __shfl_xor(sum, 32);
      const float inv = 1.0f / sum;
#pragma unroll
      for (int mt = 0; mt < 4; ++mt)
#pragma unroll
        for (int r = 0; r < 4; ++r) {
          float a = acc1[mt][r] * inv;
          asum_acc[mt][r] += a;
          a_lds[(mt * 16 + q * 4 + r) * AS + w * 16 + l] = f2bf(a);
        }
    }
    __syncthreads();

    // ---- GEMM2: vlad[64 k][128 c] += a(64 x 64s) * x^T(64s x 128c) ----
#pragma unroll
    for (int sk = 0; sk < 2; ++sk) {
      short8 afr[4];
#pragma unroll
      for (int mt = 0; mt < 4; ++mt)
        afr[mt] = *(const short8*)&a_lds[(mt * 16 + l) * AS + sk * 32 + q * 8];
#pragma unroll
      for (int nt = 0; nt < 2; ++nt) {
        const int c2 = (w * 2 + nt) * 16 + l;
        const int gsel2 = (sk * 4 + q + (c2 >> 3)) & 7;   // stored granule of s0=sk*32+q*8
        const short8 bfr = *(const short8*)&x_lds[buf][c2 * XS + (gsel2 << 3)];
#pragma unroll
        for (int mt = 0; mt < 4; ++mt)
          acc2[mt][nt] = __builtin_amdgcn_mfma_f32_16x16x32_bf16(afr[mt], bfr, acc2[mt][nt], 0, 0, 0);
      }
    }
  }

  // ---- epilogue: per-block partial slices, no atomics ----
#pragma unroll
  for (int mt = 0; mt < 4; ++mt)
#pragma unroll
    for (int r = 0; r < 4; ++r) {
      float v = asum_acc[mt][r];
      v += __shfl_xor(v, 1); v += __shfl_xor(v, 2);
      v += __shfl_xor(v, 4); v += __shfl_xor(v, 8);
      if (l == 0) asum_sh[w][mt * 16 + q * 4 + r] = v;
    }
  __syncthreads();
  if (t < NV_K)
    asum_part[(size_t)blockIdx.x * NV_K + t] =
        asum_sh[0][t] + asum_sh[1][t] + asum_sh[2][t] + asum_sh[3][t];

  float* vp = vlad_part + (size_t)blockIdx.x * (NV_K * NV_C);
#pragma unroll
  for (int mt = 0; mt < 4; ++mt)
#pragma unroll
    for (int nt = 0; nt < 2; ++nt)
#pragma unroll
      for (int r = 0; r < 4; ++r)
        vp[(mt * 16 + q * 4 + r) * NV_C + (w * 2 + nt) * 16 + l] = acc2[mt][nt][r];
}

__global__ __launch_bounds__(256) void netvlad_finalize(
    const float* __restrict__ vlad_part, const float* __restrict__ asum_part,
    const float* __restrict__ cent, float* __restrict__ out) {
  __shared__ float v_lds[NV_K * NV_C];  // 32 KB
  __shared__ float red4[256];
  __shared__ float rscale[NV_K];
  __shared__ float asum_tot[NV_K];
  __shared__ float gscale_sh;

  const int t = threadIdx.x; const int n = blockIdx.x;
  const float* vp = vlad_part + (size_t)n * SCHUNK * (NV_K * NV_C);

  if (t < NV_K) {
    float s = 0.f;
#pragma unroll
    for (int ch = 0; ch < SCHUNK; ++ch)
      s += asum_part[((size_t)n * SCHUNK + ch) * NV_K + t];
    asum_tot[t] = s;
  }
  __syncthreads();

#pragma unroll
  for (int i = 0; i < 8; ++i) {
    int vec = t + i * 256; int k = vec >> 5; int cq = vec & 31;
    float ax = 0.f, ay = 0.f, az = 0.f, aw = 0.f;
#pragma unroll
    for (int ch = 0; ch < SCHUNK; ++ch) {
      float4 p = *(const float4*)(vp + (size_t)ch * (NV_K * NV_C) + k * NV_C + cq * 4);
      ax += p.x; ay += p.y; az += p.z; aw += p.w;
    }
    float4 ce = *(const float4*)(cent + k * NV_C + cq * 4);
    float as = asum_tot[k];
    float4 v;
    v.x = ax - as * ce.x; v.y = ay - as * ce.y;
    v.z = az - as * ce.z; v.w = aw - as * ce.w;
    *(float4*)&v_lds[k * NV_C + cq * 4] = v;
  }
  __syncthreads();

  {  // per-cluster sumsq
    const int k = t >> 2, part = t & 3;
    const float* row = &v_lds[k * NV_C + part * 32];
    float ss = 0.0f;
#pragma unroll
    for (int c = 0; c < 32; ++c) { float v = row[c]; ss += v * v; }
    red4[t] = ss;
  }
  __syncthreads();
  if (t < NV_K) {
    float ss = red4[t * 4] + red4[t * 4 + 1] + red4[t * 4 + 2] + red4[t * 4 + 3];
    rscale[t] = 1.0f / fmaxf(sqrtf(ss), 1e-12f);
  }
  __syncthreads();

  float gp = 0.0f;
#pragma unroll
  for (int i = 0; i < 8; ++i) {
    int vec = t + i * 256; int k = vec >> 5; int cq = vec & 31;
    float4 v = *(const float4*)&v_lds[k * NV_C + cq * 4];
    float rs = rscale[k];
    gp += (v.x * v.x + v.y * v.y + v.z * v.z + v.w * v.w) * rs * rs;
  }
  red4[t] = gp;
  __syncthreads();
  if (t < 64) {
    float s = red4[t] + red4[t + 64] + red4[t + 128] + red4[t + 192];
#pragma unroll
    for (int o = 32; o > 0; o >>= 1) s += __shfl_down(s, o);
    if (t == 0) gscale_sh = 1.0f / fmaxf(sqrtf(s), 1e-12f);
  }
  __syncthreads();
  const float gs = gscale_sh;

#pragma unroll
  for (int i = 0; i < 8; ++i) {
    int vec = t + i * 256; int k = vec >> 5; int cq = vec & 31;
    float4 v = *(const float4*)&v_lds[k * NV_C + cq * 4];
    const float sc = rscale[k] * gs;
    v.x *= sc; v.y *= sc; v.z *= sc; v.w *= sc;
    *(float4*)(out + (size_t)n * (NV_K * NV_C) + k * NV_C + cq * 4) = v;
  }
}

extern "C" void kernel_launch(void* const* d_in, const int* in_sizes, int n_in,
                              void* d_out, int out_size, void* d_ws, size_t ws_size,
                              hipStream_t stream) {
  (void)in_sizes; (void)n_in; (void)out_size; (void)ws_size;
  const float* x      = (const float*)d_in[0];
  const float* conv_w = (const float*)d_in[1];
  const float* cent   = (const float*)d_in[2];
  float* out = (float*)d_out;

  // ws: [N*SCHUNK][K][C] partial vlads (8.4 MB) + [N*SCHUNK][K] partial asums
  float* vlad_part = (float*)d_ws;
  float* asum_part = vlad_part + (size_t)NV_N * SCHUNK * NV_K * NV_C;

  hipLaunchKernelGGL(netvlad_main, dim3(NV_N * SCHUNK), dim3(256), 0, stream,
                     x, conv_w, vlad_part, asum_part);
  hipLaunchKernelGGL(netvlad_finalize, dim3(NV_N), dim3(256), 0, stream,
                     vlad_part, asum_part, cent, out);
}